// Round 3
// baseline (454.262 us; speedup 1.0000x reference)
//
#include <hip/hip_runtime.h>

// Problem constants (B=8192, S=32, N=128, K=64, M=3)
#define BATCH 8192
#define NBLK  2048   // persistent-ish: 8 blocks/CU x 256 CUs
#define BPB   4      // batches per block (NBLK * BPB == BATCH)
#define EPSF  1e-9f

// Mapping: block handles one batch per iteration; wave w owns rows 8w..8w+7.
// Lane L: row = 8w + (L>>3), cols = (L&7)*8 .. +7 of C_p = x(32x64) @ P(64x64).
//   - x[row][k] streams from the lane's own coalesced float4 loads (8-way lane
//     duplication served by the coalescer/L1; no broadcasts, no readlane).
//   - P[k][cols] read directly from global (two dwordx4/k; 8-way intra-wave
//     dedup -> one 256B segment per k). P has no cross-block reuse, so LDS
//     staging never reduced HBM traffic -- skip it entirely.
//   - Phase-A acc registers are ALREADY in phase-B (row,sub) layout: top-4 of
//     |[x_row | C_p_row]| needs no LDS round-trip and no barriers.
__global__ __launch_bounds__(256, 8) void avl_main(
    const float* __restrict__ y_pred,
    const float* __restrict__ y_true,
    const float* __restrict__ P,   // [B][64][64]
    const float* __restrict__ X,   // [B][32][64]
    float* __restrict__ accum)     // accum[0]=violation sum, accum[1]=logmse sum
{
    __shared__ float hm_w[4];

    const int tid  = threadIdx.x;
    const int wave = tid >> 6;
    const int lane = tid & 63;
    const int rg   = lane >> 3;  // row within wave's 8
    const int cg   = lane & 7;   // col group: cols cg*8 .. cg*8+7

    for (int bi = 0; bi < BPB; ++bi) {
        const int b = blockIdx.x + NBLK * bi;
        const float* xrow = X + (size_t)b * 2048 + (wave * 8 + rg) * 64;
        const float* pcol = P + (size_t)b * 4096 + cg * 8;

        float acc[8] = {0.f, 0.f, 0.f, 0.f, 0.f, 0.f, 0.f, 0.f};

#pragma unroll 2
        for (int k = 0; k < 64; k += 4) {
            const float4 xq = *(const float4*)(xrow + k);
            const float xv[4] = {xq.x, xq.y, xq.z, xq.w};
#pragma unroll
            for (int k2 = 0; k2 < 4; ++k2) {
                const float* pr = pcol + (size_t)(k + k2) * 64;
                const float4 pa = *(const float4*)(pr);
                const float4 pb = *(const float4*)(pr + 4);
                const float xs = xv[k2];
                acc[0] = fmaf(xs, pa.x, acc[0]);
                acc[1] = fmaf(xs, pa.y, acc[1]);
                acc[2] = fmaf(xs, pa.z, acc[2]);
                acc[3] = fmaf(xs, pa.w, acc[3]);
                acc[4] = fmaf(xs, pb.x, acc[4]);
                acc[5] = fmaf(xs, pb.y, acc[5]);
                acc[6] = fmaf(xs, pb.z, acc[6]);
                acc[7] = fmaf(xs, pb.w, acc[7]);
            }
        }

        // |x| candidates for this lane's col-group (L1 hit: row already streamed)
        const float4 xa = *(const float4*)(xrow + cg * 8);
        const float4 xb = *(const float4*)(xrow + cg * 8 + 4);

        const float vals[16] = {
            fabsf(xa.x), fabsf(xa.y), fabsf(xa.z), fabsf(xa.w),
            fabsf(xb.x), fabsf(xb.y), fabsf(xb.z), fabsf(xb.w),
            fabsf(acc[0]), fabsf(acc[1]), fabsf(acc[2]), fabsf(acc[3]),
            fabsf(acc[4]), fabsf(acc[5]), fabsf(acc[6]), fabsf(acc[7])
        };

        // per-lane insertion top-4 over 16 values
        float t0 = -1.f, t1 = -1.f, t2 = -1.f, t3 = -1.f;
#pragma unroll
        for (int i = 0; i < 16; ++i) {
            float v = vals[i];
            float m;
            m = fminf(t0, v); t0 = fmaxf(t0, v); v = m;
            m = fminf(t1, v); t1 = fmaxf(t1, v); v = m;
            m = fminf(t2, v); t2 = fmaxf(t2, v); v = m;
            t3 = fmaxf(t3, v);
        }

        // merge across the 8 lanes of the row-group (xor 1,2,4): bitonic top-4
#pragma unroll
        for (int msk = 1; msk <= 4; msk <<= 1) {
            float b0 = __shfl_xor(t0, msk, 64);
            float b1 = __shfl_xor(t1, msk, 64);
            float b2 = __shfl_xor(t2, msk, 64);
            float b3 = __shfl_xor(t3, msk, 64);
            float c0v = fmaxf(t0, b3);
            float c1v = fmaxf(t1, b2);
            float c2v = fmaxf(t2, b1);
            float c3v = fmaxf(t3, b0);
            float d0 = fmaxf(c0v, c2v), d2 = fminf(c0v, c2v);
            float d1 = fmaxf(c1v, c3v), d3 = fminf(c1v, c3v);
            t0 = fmaxf(d0, d1); t1 = fminf(d0, d1);
            t2 = fmaxf(d2, d3); t3 = fminf(d2, d3);
        }

        // hm for this row (identical in all 8 lanes of the group), then
        // max over the wave's 8 rows via xor 8,16,32
        float h = t0 / (t3 + EPSF);
#pragma unroll
        for (int msk = 8; msk <= 32; msk <<= 1)
            h = fmaxf(h, __shfl_xor(h, msk, 64));

        if (lane == 0) hm_w[wave] = h;
        __syncthreads();
        if (tid == 0) {
            const float m = fmaxf(fmaxf(hm_w[0], hm_w[1]), fmaxf(hm_w[2], hm_w[3]));
            const float yp = y_pred[b];
            atomicAdd(&accum[0], fmaxf(m - yp, 0.f));
            const float lp = log2f(fmaxf(yp, EPSF));
            const float lt = log2f(fmaxf(y_true[b], EPSF));
            const float d = lt - lp;
            atomicAdd(&accum[1], d * d);
        }
        __syncthreads();  // hm_w reused next iteration
    }
}

__global__ void avl_final(const float* __restrict__ accum, float* __restrict__ out)
{
    const float vi = accum[0] * (1.0f / (float)BATCH);
    const float lm = accum[1] * (1.0f / (float)BATCH);
    out[0] = lm + 0.5f * vi;   // total_loss
    out[1] = lm;               // loss_logmse
    out[2] = vi;               // loss_violation
}

extern "C" void kernel_launch(void* const* d_in, const int* in_sizes, int n_in,
                              void* d_out, int out_size, void* d_ws, size_t ws_size,
                              hipStream_t stream)
{
    const float* y_pred = (const float*)d_in[0];
    const float* y_true = (const float*)d_in[1];
    const float* P      = (const float*)d_in[2];
    const float* X      = (const float*)d_in[3];

    float* accum = (float*)d_ws;
    hipMemsetAsync(accum, 0, 2 * sizeof(float), stream);
    avl_main<<<NBLK, 256, 0, stream>>>(y_pred, y_true, P, X, accum);
    avl_final<<<1, 1, 0, stream>>>(accum, (float*)d_out);
}

// Round 4
// 251.693 us; speedup vs baseline: 1.8048x; 1.8048x over previous
//
#include <hip/hip_runtime.h>

// Problem constants (B=8192, S=32, N=128, K=64, M=3)
#define BATCH 8192
#define NBLK  2048            // 4 batches per block, one per wave
#define EPSF  1e-9f
#define XT_LD 36              // xT leading dim (floats): 16B-aligned rows, conflict-free
#define XT_SZ (64 * XT_LD)    // 2304 floats per batch

// insertion of v into a descending top-4 (t0 >= t1 >= t2 >= t3)
__device__ __forceinline__ void ins4(float v, float& t0, float& t1, float& t2, float& t3) {
    float m;
    m = fminf(t0, v); t0 = fmaxf(t0, v); v = m;
    m = fminf(t1, v); t1 = fmaxf(t1, v); v = m;
    m = fminf(t2, v); t2 = fmaxf(t2, v); v = m;
    t3 = fmaxf(t3, v);
}

// One WAVE per batch (4 waves/block, 2048 blocks). Lane = (rg, cg): owns a
// 4-row x 8-col tile of C_p = x(32x64) @ P(64x64): rows rg*4..+3, cols cg*8..+7.
//   - x[b] staged once per wave into LDS TRANSPOSED (xt[k][row], ld=36):
//     k-loop read xt[k][rg*4..+3] is one ds_read_b128, 8 distinct bank-quads,
//     8-way lane broadcast -> conflict-free. Wave-private => no barriers.
//   - P streamed from global, register double-buffered, prefetched one
//     4-k chunk ahead (manually unrolled x2 so buffers stay in registers).
//   - 32 FMA per lane per k vs 12 operand-floats: ~3x fewer mem instructions
//     than the R3 1x8 tile; VALU floor 13.7 us/CU is the target.
//   - acc registers are already in top-4 layout; identity |x| part re-read
//     from LDS (8 ds_read_b128, once). No contended atomics: per-block
//     partials -> d_ws, reduced by avl_final.
__global__ __launch_bounds__(256) void avl_main(
    const float* __restrict__ y_pred,
    const float* __restrict__ y_true,
    const float* __restrict__ P,   // [B][64][64]
    const float* __restrict__ X,   // [B][32][64]
    float* __restrict__ partial)   // [NBLK][2]: {violation_sum, logmse_sum}
{
    __shared__ float xt[4 * XT_SZ];   // 36864 B
    __shared__ float red[8];

    const int tid  = threadIdx.x;
    const int wave = tid >> 6;
    const int lane = tid & 63;
    const int rg   = lane >> 3;   // rows rg*4 .. rg*4+3
    const int cg   = lane & 7;    // cols cg*8 .. cg*8+7
    const int b    = blockIdx.x * 4 + wave;

    float* xw = xt + wave * XT_SZ;

    // ---- stage x[b] transposed into LDS (wave-private, no barrier) ----
    {
        const float* xg = X + (size_t)b * 2048;
        float4 v[8];
#pragma unroll
        for (int c = 0; c < 8; ++c)
            v[c] = *(const float4*)(xg + c * 256 + lane * 4);
        // flat idx = c*256 + lane*4 + j  ->  row = c*4 + (lane>>4), k = (lane&15)*4 + j
        const int row = lane >> 4;
        const int k0  = (lane & 15) * 4;
#pragma unroll
        for (int c = 0; c < 8; ++c) {
            xw[(k0 + 0) * XT_LD + c * 4 + row] = v[c].x;
            xw[(k0 + 1) * XT_LD + c * 4 + row] = v[c].y;
            xw[(k0 + 2) * XT_LD + c * 4 + row] = v[c].z;
            xw[(k0 + 3) * XT_LD + c * 4 + row] = v[c].w;
        }
    }

    const float* pg = P + (size_t)b * 4096 + cg * 8;

    float acc[4][8];
#pragma unroll
    for (int i = 0; i < 4; ++i)
#pragma unroll
        for (int j = 0; j < 8; ++j) acc[i][j] = 0.f;

    // P register double-buffer: one 4-k chunk = 8 float4
    float4 bufA[4][2], bufB[4][2];
#pragma unroll
    for (int k2 = 0; k2 < 4; ++k2) {
        bufA[k2][0] = *(const float4*)(pg + k2 * 64);
        bufA[k2][1] = *(const float4*)(pg + k2 * 64 + 4);
    }

#define PREFETCH(BUF, KC)                                          \
    {                                                              \
        const int kcn = ((KC) + 1 < 16) ? (KC) + 1 : 15;           \
        const float* pn = pg + kcn * 256;                          \
        _Pragma("unroll")                                          \
        for (int k2 = 0; k2 < 4; ++k2) {                           \
            BUF[k2][0] = *(const float4*)(pn + k2 * 64);           \
            BUF[k2][1] = *(const float4*)(pn + k2 * 64 + 4);       \
        }                                                          \
    }

#define COMPUTE(BUF, KC)                                           \
    {                                                              \
        _Pragma("unroll")                                          \
        for (int k2 = 0; k2 < 4; ++k2) {                           \
            const int k = (KC) * 4 + k2;                           \
            const float4 xv = *(const float4*)(xw + k * XT_LD + rg * 4); \
            const float4 pa = BUF[k2][0];                          \
            const float4 pb = BUF[k2][1];                          \
            const float xs[4] = {xv.x, xv.y, xv.z, xv.w};          \
            const float ps[8] = {pa.x, pa.y, pa.z, pa.w,           \
                                 pb.x, pb.y, pb.z, pb.w};          \
            _Pragma("unroll")                                      \
            for (int i = 0; i < 4; ++i)                            \
                _Pragma("unroll")                                  \
                for (int j = 0; j < 8; ++j)                        \
                    acc[i][j] = fmaf(xs[i], ps[j], acc[i][j]);     \
        }                                                          \
    }

#pragma unroll
    for (int kc2 = 0; kc2 < 8; ++kc2) {
        const int kc = kc2 * 2;
        PREFETCH(bufB, kc)
        COMPUTE(bufA, kc)
        PREFETCH(bufA, kc + 1)
        COMPUTE(bufB, kc + 1)
    }
#undef PREFETCH
#undef COMPUTE

    // ---- top-4 of |[x_row | C_row]| per row ----
    // identity part: x[rg*4+i][cg*8+j] = xt[cg*8+j][rg*4+i]
    float4 xi[8];
#pragma unroll
    for (int j = 0; j < 8; ++j)
        xi[j] = *(const float4*)(xw + (cg * 8 + j) * XT_LD + rg * 4);

    float t0[4], t1[4], t2[4], t3[4];
#pragma unroll
    for (int i = 0; i < 4; ++i) { t0[i] = t1[i] = t2[i] = t3[i] = -1.f; }

#pragma unroll
    for (int j = 0; j < 8; ++j) {
        ins4(fabsf(xi[j].x), t0[0], t1[0], t2[0], t3[0]);
        ins4(fabsf(xi[j].y), t0[1], t1[1], t2[1], t3[1]);
        ins4(fabsf(xi[j].z), t0[2], t1[2], t2[2], t3[2]);
        ins4(fabsf(xi[j].w), t0[3], t1[3], t2[3], t3[3]);
    }
#pragma unroll
    for (int i = 0; i < 4; ++i)
#pragma unroll
        for (int j = 0; j < 8; ++j)
            ins4(fabsf(acc[i][j]), t0[i], t1[i], t2[i], t3[i]);

    // merge across the 8 cg-lanes (same rows): bitonic top-4, xor 1,2,4
#pragma unroll
    for (int msk = 1; msk <= 4; msk <<= 1) {
#pragma unroll
        for (int i = 0; i < 4; ++i) {
            float b0 = __shfl_xor(t0[i], msk, 64);
            float b1 = __shfl_xor(t1[i], msk, 64);
            float b2 = __shfl_xor(t2[i], msk, 64);
            float b3 = __shfl_xor(t3[i], msk, 64);
            float c0 = fmaxf(t0[i], b3);
            float c1 = fmaxf(t1[i], b2);
            float c2 = fmaxf(t2[i], b1);
            float c3 = fmaxf(t3[i], b0);
            float d0 = fmaxf(c0, c2), d2 = fminf(c0, c2);
            float d1 = fmaxf(c1, c3), d3 = fminf(c1, c3);
            t0[i] = fmaxf(d0, d1); t1[i] = fminf(d0, d1);
            t2[i] = fmaxf(d2, d3); t3[i] = fminf(d2, d3);
        }
    }

    // hm per row, max over this lane's 4 rows, then max over rg (xor 8,16,32)
    float h = -1.f;
#pragma unroll
    for (int i = 0; i < 4; ++i)
        h = fmaxf(h, t0[i] / (t3[i] + EPSF));
#pragma unroll
    for (int msk = 8; msk <= 32; msk <<= 1)
        h = fmaxf(h, __shfl_xor(h, msk, 64));

    if (lane == 0) {
        const float yp = y_pred[b];
        red[wave] = fmaxf(h - yp, 0.f);
        const float lp = log2f(fmaxf(yp, EPSF));
        const float lt = log2f(fmaxf(y_true[b], EPSF));
        const float d = lt - lp;
        red[4 + wave] = d * d;
    }
    __syncthreads();
    if (tid == 0) {
        partial[blockIdx.x * 2 + 0] = red[0] + red[1] + red[2] + red[3];
        partial[blockIdx.x * 2 + 1] = red[4] + red[5] + red[6] + red[7];
    }
}

__global__ __launch_bounds__(256) void avl_final(
    const float* __restrict__ partial, float* __restrict__ out)
{
    const int tid  = threadIdx.x;
    const int wave = tid >> 6;
    const int lane = tid & 63;
    float s0 = 0.f, s1 = 0.f;
    for (int i = tid; i < NBLK; i += 256) {
        s0 += partial[2 * i + 0];
        s1 += partial[2 * i + 1];
    }
#pragma unroll
    for (int msk = 1; msk <= 32; msk <<= 1) {
        s0 += __shfl_xor(s0, msk, 64);
        s1 += __shfl_xor(s1, msk, 64);
    }
    __shared__ float r0[4], r1[4];
    if (lane == 0) { r0[wave] = s0; r1[wave] = s1; }
    __syncthreads();
    if (tid == 0) {
        const float vi = (r0[0] + r0[1] + r0[2] + r0[3]) * (1.0f / (float)BATCH);
        const float lm = (r1[0] + r1[1] + r1[2] + r1[3]) * (1.0f / (float)BATCH);
        out[0] = lm + 0.5f * vi;   // total_loss
        out[1] = lm;               // loss_logmse
        out[2] = vi;               // loss_violation
    }
}

extern "C" void kernel_launch(void* const* d_in, const int* in_sizes, int n_in,
                              void* d_out, int out_size, void* d_ws, size_t ws_size,
                              hipStream_t stream)
{
    const float* y_pred = (const float*)d_in[0];
    const float* y_true = (const float*)d_in[1];
    const float* P      = (const float*)d_in[2];
    const float* X      = (const float*)d_in[3];

    float* partial = (float*)d_ws;   // NBLK*2 floats = 16 KB
    avl_main<<<NBLK, 256, 0, stream>>>(y_pred, y_true, P, X, partial);
    avl_final<<<1, 256, 0, stream>>>(partial, (float*)d_out);
}

// Round 5
// 245.896 us; speedup vs baseline: 1.8474x; 1.0236x over previous
//
#include <hip/hip_runtime.h>

// Problem constants (B=8192, S=32, N=128, K=64, M=3)
#define BATCH 8192
#define NBLK  2048            // 4 batches per block, one per wave
#define EPSF  1e-9f
#define C_LD  68              // |C| LDS tile leading dim: breaks column-access conflicts
#define C_SZ  (32 * C_LD)     // 2176 floats per wave

typedef float floatx16 __attribute__((ext_vector_type(16)));
typedef short shortx8  __attribute__((ext_vector_type(8)));

// insert v into descending top-4
__device__ __forceinline__ void ins4(float v, float& t0, float& t1, float& t2, float& t3) {
    float m;
    m = fminf(t0, v); t0 = fmaxf(t0, v); v = m;
    m = fminf(t1, v); t1 = fmaxf(t1, v); v = m;
    m = fminf(t2, v); t2 = fmaxf(t2, v); v = m;
    t3 = fmaxf(t3, v);
}

// merge a second descending top-4 (b0..b3) into t0..t3 (bitonic)
__device__ __forceinline__ void merge4(float& t0, float& t1, float& t2, float& t3,
                                       float b0, float b1, float b2, float b3) {
    float c0 = fmaxf(t0, b3);
    float c1 = fmaxf(t1, b2);
    float c2 = fmaxf(t2, b1);
    float c3 = fmaxf(t3, b0);
    float d0 = fmaxf(c0, c2), d2 = fminf(c0, c2);
    float d1 = fmaxf(c1, c3), d3 = fminf(c1, c3);
    t0 = fmaxf(d0, d1); t1 = fminf(d0, d1);
    t2 = fmaxf(d2, d3); t3 = fminf(d2, d3);
}

// One WAVE per batch. C = x(32x64) @ P(64x64) via split-bf16 MFMA:
//   x = hi + lo (bf16 truncation split, residual exact in fp32);
//   C = hi*hi + hi*lo + lo*hi accumulated fp32 (rel err ~1e-5).
// Fragments (32x32x16_bf16): A[m=lane&31][k=(lane>>5)*8+j],
//   B[k=(lane>>5)*8+j][n=lane&31], C/D col=lane&31,
//   row=(reg&3)+8*(reg>>2)+4*(lane>>5).
// x loads are coalesced float4 directly in A-order (no LDS transpose).
// P loads: 32 scalar dwords/tile, 2x128B coalesced segments per inst.
// |C| goes through a wave-private LDS tile (ld=68) for row-major top-4;
// |x| candidates are folded in from registers before the MFMAs.
__global__ __launch_bounds__(256) void avl_main(
    const float* __restrict__ y_pred,
    const float* __restrict__ y_true,
    const float* __restrict__ P,   // [B][64][64]
    const float* __restrict__ X,   // [B][32][64]
    float* __restrict__ partial)   // [NBLK][2]: {violation_sum, logmse_sum}
{
    __shared__ float csh[4 * C_SZ];   // 34816 B
    __shared__ float red[8];

    const int tid  = threadIdx.x;
    const int wave = tid >> 6;
    const int lane = tid & 63;
    const int kg   = lane >> 5;   // K-half: this lane covers k = kg*8 + 16*ks + j
    const int m    = lane & 31;   // A row index == B col index == C col index
    const int b    = blockIdx.x * 4 + wave;

    float* Cw = csh + wave * C_SZ;

    // ---- load x in A-fragment order (8 coalesced dwordx4) ----
    const float* xg = X + (size_t)b * 2048 + m * 64 + kg * 8;
    float4 xa[4], xb[4];
#pragma unroll
    for (int ks = 0; ks < 4; ++ks) {
        xa[ks] = *(const float4*)(xg + ks * 16);
        xb[ks] = *(const float4*)(xg + ks * 16 + 4);
    }

    // ---- convert to hi/lo bf16 A-frags; fold |x| into the local top-4 ----
    float t0 = -1.f, t1 = -1.f, t2 = -1.f, t3 = -1.f;
    shortx8 ahi[4], alo[4];
#pragma unroll
    for (int ks = 0; ks < 4; ++ks) {
        const float v[8] = { xa[ks].x, xa[ks].y, xa[ks].z, xa[ks].w,
                             xb[ks].x, xb[ks].y, xb[ks].z, xb[ks].w };
#pragma unroll
        for (int i = 0; i < 8; ++i) {
            const float x = v[i];
            const unsigned bits = __float_as_uint(x);
            ahi[ks][i] = (short)(bits >> 16);
            const float hif = __uint_as_float(bits & 0xFFFF0000u);
            const float lof = x - hif;
            alo[ks][i] = (short)(__float_as_uint(lof) >> 16);
            ins4(fabsf(x), t0, t1, t2, t3);
        }
    }

    // ---- two 32-col tiles of C ----
    const float* pg = P + (size_t)b * 4096 + (kg * 8) * 64 + m;
#pragma unroll
    for (int tile = 0; tile < 2; ++tile) {
        const float* pt = pg + tile * 32;
        float pv[32];
#pragma unroll
        for (int ks = 0; ks < 4; ++ks)
#pragma unroll
            for (int i = 0; i < 8; ++i)
                pv[ks * 8 + i] = pt[(ks * 16 + i) * 64];

        shortx8 bhi[4], blo[4];
#pragma unroll
        for (int ks = 0; ks < 4; ++ks)
#pragma unroll
            for (int i = 0; i < 8; ++i) {
                const float p = pv[ks * 8 + i];
                const unsigned bits = __float_as_uint(p);
                bhi[ks][i] = (short)(bits >> 16);
                const float hif = __uint_as_float(bits & 0xFFFF0000u);
                const float lof = p - hif;
                blo[ks][i] = (short)(__float_as_uint(lof) >> 16);
            }

        floatx16 acc;
#pragma unroll
        for (int r = 0; r < 16; ++r) acc[r] = 0.f;
#pragma unroll
        for (int ks = 0; ks < 4; ++ks) {
            acc = __builtin_amdgcn_mfma_f32_32x32x16_bf16(alo[ks], bhi[ks], acc, 0, 0, 0);
            acc = __builtin_amdgcn_mfma_f32_32x32x16_bf16(ahi[ks], blo[ks], acc, 0, 0, 0);
            acc = __builtin_amdgcn_mfma_f32_32x32x16_bf16(ahi[ks], bhi[ks], acc, 0, 0, 0);
        }

        // |C| -> LDS row-major (writes: 32 lanes hit 32 distinct banks; 2-way
        // aliasing between half-waves is free)
#pragma unroll
        for (int reg = 0; reg < 16; ++reg) {
            const int row = (reg & 3) + 8 * (reg >> 2) + 4 * kg;
            Cw[row * C_LD + tile * 32 + m] = fabsf(acc[reg]);
        }
    }

    // ---- top-4 of |[x_row | C_row]|: lane handles row m, C-cols kg*32..+31 ----
    const float* cr = Cw + m * C_LD + kg * 32;
#pragma unroll
    for (int t = 0; t < 8; ++t) {
        const float4 c = *(const float4*)(cr + 4 * t);
        ins4(c.x, t0, t1, t2, t3);
        ins4(c.y, t0, t1, t2, t3);
        ins4(c.z, t0, t1, t2, t3);
        ins4(c.w, t0, t1, t2, t3);
    }

    // merge complementary half (lane L and L+32 cover disjoint 64-value sets)
    {
        const float b0 = __shfl_xor(t0, 32, 64);
        const float b1 = __shfl_xor(t1, 32, 64);
        const float b2 = __shfl_xor(t2, 32, 64);
        const float b3 = __shfl_xor(t3, 32, 64);
        merge4(t0, t1, t2, t3, b0, b1, b2, b3);
    }

    float h = t0 / (t3 + EPSF);
#pragma unroll
    for (int msk = 1; msk <= 16; msk <<= 1)
        h = fmaxf(h, __shfl_xor(h, msk, 64));

    if (lane == 0) {
        const float yp = y_pred[b];
        red[wave] = fmaxf(h - yp, 0.f);
        const float lp = log2f(fmaxf(yp, EPSF));
        const float lt = log2f(fmaxf(y_true[b], EPSF));
        const float d = lt - lp;
        red[4 + wave] = d * d;
    }
    __syncthreads();
    if (tid == 0) {
        partial[blockIdx.x * 2 + 0] = red[0] + red[1] + red[2] + red[3];
        partial[blockIdx.x * 2 + 1] = red[4] + red[5] + red[6] + red[7];
    }
}

__global__ __launch_bounds__(256) void avl_final(
    const float* __restrict__ partial, float* __restrict__ out)
{
    const int tid  = threadIdx.x;
    const int wave = tid >> 6;
    const int lane = tid & 63;
    float s0 = 0.f, s1 = 0.f;
    for (int i = tid; i < NBLK; i += 256) {
        s0 += partial[2 * i + 0];
        s1 += partial[2 * i + 1];
    }
#pragma unroll
    for (int msk = 1; msk <= 32; msk <<= 1) {
        s0 += __shfl_xor(s0, msk, 64);
        s1 += __shfl_xor(s1, msk, 64);
    }
    __shared__ float r0[4], r1[4];
    if (lane == 0) { r0[wave] = s0; r1[wave] = s1; }
    __syncthreads();
    if (tid == 0) {
        const float vi = (r0[0] + r0[1] + r0[2] + r0[3]) * (1.0f / (float)BATCH);
        const float lm = (r1[0] + r1[1] + r1[2] + r1[3]) * (1.0f / (float)BATCH);
        out[0] = lm + 0.5f * vi;   // total_loss
        out[1] = lm;               // loss_logmse
        out[2] = vi;               // loss_violation
    }
}

extern "C" void kernel_launch(void* const* d_in, const int* in_sizes, int n_in,
                              void* d_out, int out_size, void* d_ws, size_t ws_size,
                              hipStream_t stream)
{
    const float* y_pred = (const float*)d_in[0];
    const float* y_true = (const float*)d_in[1];
    const float* P      = (const float*)d_in[2];
    const float* X      = (const float*)d_in[3];

    float* partial = (float*)d_ws;   // NBLK*2 floats = 16 KB
    avl_main<<<NBLK, 256, 0, stream>>>(y_pred, y_true, P, X, partial);
    avl_final<<<1, 256, 0, stream>>>(partial, (float*)d_out);
}